// Round 3
// baseline (1556.998 us; speedup 1.0000x reference)
//
#include <hip/hip_runtime.h>
#include <hip/hip_bf16.h>
#include <stdint.h>

// Problem constants (from reference setup_inputs)
#define JT 5           // edge types
#define NE 150000      // edges per type
#define NC 2           // channels
#define NDIM 4096      // nodes
#define NNZ (JT * NE)  // 750000 raw edges (duplicates kept; linearity handles them)
constexpr size_t MAT = (size_t)NDIM * NDIM;   // 16,777,216
constexpr size_t HN  = (size_t)NC * MAT;      // 33,554,432 (H element count)

// ---------------------------------------------------------------- softmax
// f1 = softmax(w1, axis=1), f2 = softmax(w2, axis=1) -> fbuf (for fill_k)
// and d_out tail (outputs 1 and 2).
__global__ void softmax_k(const float* __restrict__ w1, const float* __restrict__ w2,
                          float* __restrict__ fbuf, float* __restrict__ out_tail) {
    int t = threadIdx.x;
    if (t < 2 * NC) {
        const float* w = (t < NC) ? w1 : w2;
        int c = t % NC;
        float v[JT];
        float mx = -1e30f;
        for (int j = 0; j < JT; ++j) { v[j] = w[c * JT + j]; mx = fmaxf(mx, v[j]); }
        float s = 0.f;
        for (int j = 0; j < JT; ++j) { v[j] = expf(v[j] - mx); s += v[j]; }
        float inv = 1.0f / s;
        for (int j = 0; j < JT; ++j) {
            float f = v[j] * inv;
            fbuf[t * JT + j] = f;       // rows: f1c0, f1c1, f2c0, f2c1
            out_tail[t * JT + j] = f;   // flat (f1, f2) output order
        }
    }
}

// ---------------------------------------------------------------- histogram
// counts[r] += 1 for every edge source r (counts lives in `work`).
__global__ void hist_k(const int* __restrict__ ei, uint32_t* __restrict__ work) {
    int idx = blockIdx.x * blockDim.x + threadIdx.x;
    if (idx >= NNZ) return;
    int j = idx / NE;
    int e = idx - j * NE;
    int r = ei[(size_t)j * 2 * NE + e];
    atomicAdd(&work[r], 1u);
}

// ---------------------------------------------------------------- scan
// Single-workgroup exclusive scan of 4096 counts (in `work`).
// Writes rowptr[0..4096] and overwrites work[i] = rowptr[i] (fill cursors).
__global__ __launch_bounds__(256) void scan_k(uint32_t* __restrict__ work,
                                              uint32_t* __restrict__ rowptr) {
    __shared__ uint32_t part[256];
    int t = threadIdx.x, lane = t & 63;
    uint32_t tot = 0;
#pragma unroll
    for (int i = 0; i < 16; ++i) tot += work[t * 16 + i];
    part[t] = tot;
    __syncthreads();
    if (t < 64) {  // wave 0 scans the 256 partials, 4 per lane
        uint32_t v0 = part[t * 4], v1 = part[t * 4 + 1],
                 v2 = part[t * 4 + 2], v3 = part[t * 4 + 3];
        uint32_t s = v0 + v1 + v2 + v3;
        uint32_t inc = s;
        for (int d = 1; d < 64; d <<= 1) {
            uint32_t n = __shfl_up(inc, d);
            if (lane >= d) inc += n;
        }
        uint32_t excl = inc - s;
        part[t * 4]     = excl;
        part[t * 4 + 1] = excl + v0;
        part[t * 4 + 2] = excl + v0 + v1;
        part[t * 4 + 3] = excl + v0 + v1 + v2;
    }
    __syncthreads();
    uint32_t base = part[t];
#pragma unroll
    for (int i = 0; i < 16; ++i) {
        uint32_t idx = t * 16 + i;
        uint32_t cnt = work[idx];   // read count BEFORE overwriting
        rowptr[idx] = base;
        work[idx]   = base;
        base += cnt;
    }
    if (t == 255) rowptr[4096] = base;   // == NNZ
}

// ---------------------------------------------------------------- CSR fill
// One CSR keyed by source node serves BOTH matrices (identical sparsity):
// per slot: col (u16), a1 = (f1c0*v, f1c1*v) fp32x2, a2 = (f2c0*v, f2c1*v) bf16x2.
__device__ __forceinline__ uint32_t pack_bf16x2(float x, float y) {
    uint16_t bx = __builtin_bit_cast(uint16_t, (__bf16)x);
    uint16_t by = __builtin_bit_cast(uint16_t, (__bf16)y);
    return ((uint32_t)by << 16) | bx;
}

__global__ void fill_k(const int* __restrict__ ei, const float* __restrict__ ev,
                       const float* __restrict__ fbuf, uint32_t* __restrict__ work,
                       uint16_t* __restrict__ cols, float2* __restrict__ a1v,
                       uint32_t* __restrict__ a2v) {
    int idx = blockIdx.x * blockDim.x + threadIdx.x;
    if (idx >= NNZ) return;
    int j = idx / NE;
    int e = idx - j * NE;
    int r = ei[(size_t)j * 2 * NE + e];
    int c = ei[(size_t)j * 2 * NE + NE + e];
    float v = ev[idx];
    uint32_t p = atomicAdd(&work[r], 1u);
    cols[p] = (uint16_t)c;
    a1v[p] = make_float2(fbuf[j] * v, fbuf[JT + j] * v);
    a2v[p] = pack_bf16x2(fbuf[2 * JT + j] * v, fbuf[3 * JT + j] * v);
}

// ---------------------------------------------------------------- SpMM
// H[c][m][:] = Sigma_{e1=(m->k)} a1c(e1) * row_k(A2c), accumulated in a
// per-block LDS dense row (both channels). 32 KiB LDS -> 5 blocks/CU.
// Outer edges split across the 4 waves; inner segment across 64 lanes.
__global__ __launch_bounds__(256) void spmm_k(const uint32_t* __restrict__ rowptr,
                                              const uint16_t* __restrict__ cols,
                                              const float2* __restrict__ a1v,
                                              const uint32_t* __restrict__ a2v,
                                              float* __restrict__ H) {
    __shared__ float h0[NDIM];
    __shared__ float h1[NDIM];
    const int m = blockIdx.x;
    const int t = threadIdx.x, lane = t & 63, wv = t >> 6;

    for (int i = t; i < NDIM; i += 256) { h0[i] = 0.f; h1[i] = 0.f; }
    __syncthreads();

    const uint32_t s0 = rowptr[m], s1 = rowptr[m + 1];
    for (uint32_t o = s0 + wv; o < s1; o += 4) {
        const int k = cols[o];                 // broadcast across wave
        const float2 a = a1v[o];
        const uint32_t t0 = rowptr[k], t1 = rowptr[k + 1];
        for (uint32_t i = t0 + lane; i < t1; i += 64) {
            const int n = cols[i];
            const uint32_t p = a2v[i];
            const float b0 = __builtin_bit_cast(float, p << 16);
            const float b1 = __builtin_bit_cast(float, p & 0xffff0000u);
            atomicAdd(&h0[n], a.x * b0);
            atomicAdd(&h1[n], a.y * b1);
        }
    }
    __syncthreads();

    float* H0 = H + (size_t)m * NDIM;
    float* H1 = H + MAT + (size_t)m * NDIM;
    for (int i = t; i < NDIM; i += 256) { H0[i] = h0[i]; H1[i] = h1[i]; }
}

// ---------------------------------------------------------------- launch
extern "C" void kernel_launch(void* const* d_in, const int* in_sizes, int n_in,
                              void* d_out, int out_size, void* d_ws, size_t ws_size,
                              hipStream_t stream) {
    const int*   ei = (const int*)d_in[0];
    const float* ev = (const float*)d_in[1];
    const float* w1 = (const float*)d_in[2];
    const float* w2 = (const float*)d_in[3];
    float* out = (float*)d_out;

    // ws layout (all 16B-aligned): a1v | a2v | rowptr | work | cols | fbuf
    char* ws = (char*)d_ws;
    float2*   a1v    = (float2*)(ws);                        //  6,000,000 B
    uint32_t* a2v    = (uint32_t*)(ws + 6000000);            //  3,000,000 B
    uint32_t* rowptr = (uint32_t*)(ws + 9000000);            //     16,388 B
    uint32_t* work   = (uint32_t*)(ws + 9016400);            //     16,384 B
    uint16_t* cols   = (uint16_t*)(ws + 9032800);            //  1,500,000 B
    float*    fbuf   = (float*)(ws + 10532800);              //         80 B
    if (ws_size < 10540000) return;  // distinctive failure: output stays poisoned

    softmax_k<<<dim3(1), dim3(64), 0, stream>>>(w1, w2, fbuf, out + HN);

    hipMemsetAsync(work, 0, NDIM * sizeof(uint32_t), stream);

    const int nb = (NNZ + 255) / 256;
    hist_k<<<dim3(nb), dim3(256), 0, stream>>>(ei, work);
    scan_k<<<dim3(1), dim3(256), 0, stream>>>(work, rowptr);
    fill_k<<<dim3(nb), dim3(256), 0, stream>>>(ei, ev, fbuf, work, cols, a1v, a2v);
    spmm_k<<<dim3(NDIM), dim3(256), 0, stream>>>(rowptr, cols, a1v, a2v, out);
}

// Round 5
// 474.854 us; speedup vs baseline: 3.2789x; 3.2789x over previous
//
#include <hip/hip_runtime.h>
#include <hip/hip_bf16.h>
#include <stdint.h>

// Problem constants (from reference setup_inputs)
#define JT 5           // edge types
#define NE 150000      // edges per type
#define NC 2           // channels
#define NDIM 4096      // nodes
#define KDIM 4096
#define NNZ (JT * NE)  // 750000 raw edges (duplicates fine: linearity == coalesce)
constexpr size_t MAT = (size_t)NDIM * NDIM;   // 16,777,216
constexpr size_t HN  = (size_t)NC * MAT;      // 33,554,432 (H element count)

typedef __bf16 bf16x8 __attribute__((ext_vector_type(8)));
typedef float  f32x4  __attribute__((ext_vector_type(4)));

// ---------------------------------------------------------------- softmax
__global__ void softmax_k(const float* __restrict__ w1, const float* __restrict__ w2,
                          float* __restrict__ fbuf, float* __restrict__ out_tail) {
    int t = threadIdx.x;
    if (t < 2 * NC) {
        const float* w = (t < NC) ? w1 : w2;
        int c = t % NC;
        float v[JT];
        float mx = -1e30f;
        for (int j = 0; j < JT; ++j) { v[j] = w[c * JT + j]; mx = fmaxf(mx, v[j]); }
        float s = 0.f;
        for (int j = 0; j < JT; ++j) { v[j] = expf(v[j] - mx); s += v[j]; }
        float inv = 1.0f / s;
        for (int j = 0; j < JT; ++j) {
            float f = v[j] * inv;
            fbuf[t * JT + j] = f;       // rows: f1c0, f1c1, f2c0, f2c1
            out_tail[t * JT + j] = f;   // flat (f1, f2) output order
        }
    }
}

// ---------------------------------------------------------------- histogram
// counts[r] (A1 rows, keyed by src) and counts[4096+c] (A2^T rows, keyed by dst)
__global__ void hist2_k(const int* __restrict__ ei, uint32_t* __restrict__ work) {
    int idx = blockIdx.x * blockDim.x + threadIdx.x;
    if (idx >= NNZ) return;
    int j = idx / NE;
    int e = idx - j * NE;
    int r = ei[(size_t)j * 2 * NE + e];
    int c = ei[(size_t)j * 2 * NE + NE + e];
    atomicAdd(&work[r], 1u);
    atomicAdd(&work[NDIM + c], 1u);
}

// ---------------------------------------------------------------- scan
// Single-workgroup exclusive scan of 4096 counts.
// Writes rowptr[0..4096] and overwrites work[i] = rowptr[i] (fill cursors).
__global__ __launch_bounds__(256) void scan_k(uint32_t* __restrict__ work,
                                              uint32_t* __restrict__ rowptr) {
    __shared__ uint32_t part[256];
    int t = threadIdx.x, lane = t & 63;
    uint32_t tot = 0;
#pragma unroll
    for (int i = 0; i < 16; ++i) tot += work[t * 16 + i];
    part[t] = tot;
    __syncthreads();
    if (t < 64) {  // wave 0 scans the 256 partials, 4 per lane
        uint32_t v0 = part[t * 4], v1 = part[t * 4 + 1],
                 v2 = part[t * 4 + 2], v3 = part[t * 4 + 3];
        uint32_t s = v0 + v1 + v2 + v3;
        uint32_t inc = s;
        for (int d = 1; d < 64; d <<= 1) {
            uint32_t n = __shfl_up(inc, d);
            if (lane >= d) inc += n;
        }
        uint32_t excl = inc - s;
        part[t * 4]     = excl;
        part[t * 4 + 1] = excl + v0;
        part[t * 4 + 2] = excl + v0 + v1;
        part[t * 4 + 3] = excl + v0 + v1 + v2;
    }
    __syncthreads();
    uint32_t base = part[t];
#pragma unroll
    for (int i = 0; i < 16; ++i) {
        uint32_t idx = t * 16 + i;
        uint32_t cnt = work[idx];   // read count BEFORE overwriting
        rowptr[idx] = base;
        work[idx]   = base;
        base += cnt;
    }
    if (t == 255) rowptr[4096] = base;   // == NNZ
}

// ---------------------------------------------------------------- CSR fill
// Two CSRs share one edge pass. Entry = (col | j<<12) u16 + raw v f32;
// softmax weight applied at build time (both channels from the same entry).
__global__ void fill2_k(const int* __restrict__ ei, const float* __restrict__ ev,
                        uint32_t* __restrict__ work,
                        uint16_t* __restrict__ keyR, float* __restrict__ valR,
                        uint16_t* __restrict__ keyC, float* __restrict__ valC) {
    int idx = blockIdx.x * blockDim.x + threadIdx.x;
    if (idx >= NNZ) return;
    int j = idx / NE;
    int e = idx - j * NE;
    int r = ei[(size_t)j * 2 * NE + e];
    int c = ei[(size_t)j * 2 * NE + NE + e];
    float v = ev[idx];
    uint32_t p = atomicAdd(&work[r], 1u);
    keyR[p] = (uint16_t)(c | (j << 12));
    valR[p] = v;
    uint32_t q = atomicAdd(&work[NDIM + c], 1u);
    keyC[q] = (uint16_t)(r | (j << 12));
    valC[q] = v;
}

// ---------------------------------------------------------------- dense build
// One block per output row: accumulate CSR entries into a 2-channel fp32 LDS
// row (f[j]-weighted), then write both channels' bf16 rows directly.
__global__ __launch_bounds__(256) void build_k(const uint32_t* __restrict__ rowptr,
                                               const uint16_t* __restrict__ key,
                                               const float* __restrict__ val,
                                               const float* __restrict__ f2,  // [2][JT]
                                               __bf16* __restrict__ dst) {
    __shared__ float h0[NDIM];
    __shared__ float h1[NDIM];
    const int m = blockIdx.x;
    const int t = threadIdx.x;

    float f0[JT], f1[JT];
#pragma unroll
    for (int j = 0; j < JT; ++j) { f0[j] = f2[j]; f1[j] = f2[JT + j]; }

    for (int i = t; i < NDIM; i += 256) { h0[i] = 0.f; h1[i] = 0.f; }
    __syncthreads();

    const uint32_t s0 = rowptr[m], s1 = rowptr[m + 1];
    for (uint32_t i = s0 + t; i < s1; i += 256) {
        uint32_t k = key[i];
        float v = val[i];
        int col = k & 0xFFF, j = k >> 12;
        atomicAdd(&h0[col], f0[j] * v);
        atomicAdd(&h1[col], f1[j] * v);
    }
    __syncthreads();

    __bf16* d0 = dst + (size_t)m * NDIM;
    __bf16* d1 = dst + MAT + (size_t)m * NDIM;
    for (int i = t; i < NDIM / 8; i += 256) {
        bf16x8 o0, o1;
#pragma unroll
        for (int j = 0; j < 8; ++j) {
            o0[j] = (__bf16)h0[i * 8 + j];
            o1[j] = (__bf16)h1[i * 8 + j];
        }
        *(bf16x8*)(d0 + i * 8) = o0;
        *(bf16x8*)(d1 + i * 8) = o1;
    }
}

// ---------------------------------------------------------------- GEMM
// Round-2 verified kernel, verbatim: 256x256 8-phase, BK=64, 8 waves,
// 128 KiB dbuf LDS, counted vmcnt(2), XOR swizzle both-sides, setprio.
#define BM 256
#define BN 256
#define BK 64
#define NT (KDIM / BK)
#define TILE_E (BM * BK)

__device__ __forceinline__ void gl_lds16(const __bf16* g, __bf16* l) {
    __builtin_amdgcn_global_load_lds(
        (const __attribute__((address_space(1))) void*)(uintptr_t)g,
        (__attribute__((address_space(3))) void*)l, 16, 0, 0);
}

#define PHASE(MH, KS, READB, ...) do {                                            \
    _Pragma("unroll")                                                             \
    for (int i = 0; i < 4; ++i)                                                   \
        af[i] = *(const bf16x8*)(ldsAc +                                          \
            ((((rA + ((MH)*4 + i) * 16) * 128) + (KS)*64 + kb) ^ swz));           \
    if (READB) {                                                                  \
        _Pragma("unroll")                                                         \
        for (int n = 0; n < 4; ++n)                                               \
            bfr[n] = *(const bf16x8*)(ldsBc +                                     \
                ((((rB + n * 16) * 128) + (KS)*64 + kb) ^ swz));                  \
    }                                                                             \
    __VA_ARGS__;                                                                  \
    __builtin_amdgcn_s_barrier();                                                 \
    asm volatile("s_waitcnt lgkmcnt(0)" ::: "memory");                            \
    __builtin_amdgcn_s_setprio(1);                                                \
    _Pragma("unroll")                                                             \
    for (int i = 0; i < 4; ++i)                                                   \
        _Pragma("unroll")                                                         \
        for (int n = 0; n < 4; ++n)                                               \
            acc[(MH)*4 + i][n] = __builtin_amdgcn_mfma_f32_16x16x32_bf16(         \
                af[i], bfr[n], acc[(MH)*4 + i][n], 0, 0, 0);                      \
    __builtin_amdgcn_s_setprio(0);                                                \
    __builtin_amdgcn_s_barrier();                                                 \
} while (0)

__global__ __launch_bounds__(512, 2) void gemm_k(const __bf16* __restrict__ A,
                                                 const __bf16* __restrict__ B,
                                                 float* __restrict__ C) {
    __shared__ __align__(16) __bf16 sm[4 * TILE_E];

    const int u    = threadIdx.x;
    const int lane = u & 63;
    const int wv   = u >> 6;
    const int wm   = wv >> 2;
    const int wn   = wv & 3;
    const size_t matoff = (size_t)blockIdx.z * MAT;
    const size_t brow   = (size_t)blockIdx.y * BM;
    const size_t bcol   = (size_t)blockIdx.x * BN;

    const int srow = u >> 3;
    const int kc   = (u & 7) ^ (srow & 7);
    const __bf16* Abase = A + matoff + (brow + srow) * KDIM + kc * 8;
    const __bf16* Bbase = B + matoff + (bcol + srow) * KDIM + kc * 8;

    char* const smb = (char*)sm;
    auto issueA = [&](int unit, int tt) {
        const __bf16* src = Abase + (size_t)unit * 64 * KDIM + (size_t)tt * BK;
        __bf16* dst = (__bf16*)(smb + (tt & 1) * 65536 + unit * 8192 + wv * 1024);
        gl_lds16(src, dst);
    };
    auto issueB = [&](int unit, int tt) {
        const __bf16* src = Bbase + (size_t)unit * 64 * KDIM + (size_t)tt * BK;
        __bf16* dst = (__bf16*)(smb + (tt & 1) * 65536 + 32768 + unit * 8192 + wv * 1024);
        gl_lds16(src, dst);
    };

    const int rA  = wm * 128 + (lane & 15);
    const int rB  = wn * 64  + (lane & 15);
    const int kb  = (lane >> 4) * 16;
    const int swz = (lane & 7) << 4;

    f32x4 acc[8][4];
#pragma unroll
    for (int m = 0; m < 8; ++m)
#pragma unroll
        for (int n = 0; n < 4; ++n) acc[m][n] = (f32x4){0.f, 0.f, 0.f, 0.f};

    bf16x8 af[4], bfr[4];

#pragma unroll
    for (int i = 0; i < 4; ++i) issueA(i, 0);
#pragma unroll
    for (int i = 0; i < 4; ++i) issueB(i, 0);

    for (int t = 0; t < NT; ++t) {
        const char* ldsAc = smb + (t & 1) * 65536;
        const char* ldsBc = ldsAc + 32768;
        const int nxt = t + 1;
        const bool hasNext = nxt < NT;

        if (hasNext) {
            issueA(0, nxt); issueA(1, nxt);
            asm volatile("s_waitcnt vmcnt(2)" ::: "memory");
        } else {
            asm volatile("s_waitcnt vmcnt(0)" ::: "memory");
        }
        __builtin_amdgcn_s_barrier();
        asm volatile("" ::: "memory");

        PHASE(0, 0, true,  if (hasNext) { issueA(2, nxt); issueA(3, nxt);
                                          issueB(0, nxt); issueB(1, nxt); });
        PHASE(1, 0, false, if (hasNext) { issueB(2, nxt); issueB(3, nxt); });
        PHASE(0, 1, true,  );
        PHASE(1, 1, false, );
    }

    float* Cc = C + matoff;
#pragma unroll
    for (int m = 0; m < 8; ++m) {
        int orow0 = (int)brow + wm * 128 + m * 16 + (lane >> 4) * 4;
#pragma unroll
        for (int n = 0; n < 4; ++n) {
            int ocol = (int)bcol + wn * 64 + n * 16 + (lane & 15);
            float* p = Cc + (size_t)orow0 * NDIM + ocol;
#pragma unroll
            for (int jj = 0; jj < 4; ++jj) p[(size_t)jj * NDIM] = acc[m][n][jj];
        }
    }
}

// ---------------------------------------------------------------- launch
extern "C" void kernel_launch(void* const* d_in, const int* in_sizes, int n_in,
                              void* d_out, int out_size, void* d_ws, size_t ws_size,
                              hipStream_t stream) {
    const int*   ei = (const int*)d_in[0];
    const float* ev = (const float*)d_in[1];
    const float* w1 = (const float*)d_in[2];
    const float* w2 = (const float*)d_in[3];
    float* out = (float*)d_out;

    // ws: A1 bf16 (67MB) | A2T bf16 (67MB) | fbuf (20 floats) — round-2 footprint
    char* ws = (char*)d_ws;
    __bf16* A1b  = (__bf16*)ws;
    __bf16* A2b  = (__bf16*)(ws + HN * sizeof(__bf16));
    float*  fbuf = (float*)(ws + 2 * HN * sizeof(__bf16));
    size_t needed = 2 * HN * sizeof(__bf16) + 32 * sizeof(float);
    if (ws_size < needed) return;

    // CSR scratch lives in the dead H region of d_out (GEMM overwrites it last).
    char* sc = (char*)d_out;
    uint16_t* keyR    = (uint16_t*)(sc);                 // 1,500,000 B
    uint16_t* keyC    = (uint16_t*)(sc + 1500000);       // 1,500,000 B
    float*    valR    = (float*)(sc + 3000000);          // 3,000,000 B
    float*    valC    = (float*)(sc + 6000000);          // 3,000,000 B
    uint32_t* rowptrR = (uint32_t*)(sc + 9000000);       //    16,388 B
    uint32_t* rowptrC = (uint32_t*)(sc + 9016400);       //    16,388 B
    uint32_t* work    = (uint32_t*)(sc + 9032800);       //    32,768 B (R|C counts)

    softmax_k<<<dim3(1), dim3(64), 0, stream>>>(w1, w2, fbuf, out + HN);

    hipMemsetAsync(work, 0, 2 * NDIM * sizeof(uint32_t), stream);

    const int nb = (NNZ + 255) / 256;
    hist2_k<<<dim3(nb), dim3(256), 0, stream>>>(ei, work);
    scan_k<<<dim3(1), dim3(256), 0, stream>>>(work, rowptrR);
    scan_k<<<dim3(1), dim3(256), 0, stream>>>(work + NDIM, rowptrC);
    fill2_k<<<dim3(nb), dim3(256), 0, stream>>>(ei, ev, work, keyR, valR, keyC, valC);

    build_k<<<dim3(NDIM), dim3(256), 0, stream>>>(rowptrR, keyR, valR, fbuf,          A1b);
    build_k<<<dim3(NDIM), dim3(256), 0, stream>>>(rowptrC, keyC, valC, fbuf + 2 * JT, A2b);

    gemm_k<<<dim3(NDIM / BN, NDIM / BM, NC), dim3(512), 0, stream>>>(A1b, A2b, out);
}

// Round 6
// 387.569 us; speedup vs baseline: 4.0173x; 1.2252x over previous
//
#include <hip/hip_runtime.h>
#include <hip/hip_bf16.h>
#include <stdint.h>

// Problem constants (from reference setup_inputs)
#define JT 5           // edge types
#define NE 150000      // edges per type
#define NC 2           // channels
#define NDIM 4096      // nodes
#define KDIM 4096
#define NNZ (JT * NE)  // 750000 raw edges (duplicates fine: linearity == coalesce)
constexpr size_t MAT = (size_t)NDIM * NDIM;   // 16,777,216
constexpr size_t HN  = (size_t)NC * MAT;      // 33,554,432 (H element count)

typedef __bf16 bf16x8 __attribute__((ext_vector_type(8)));
typedef float  f32x4  __attribute__((ext_vector_type(4)));

// ---------------------------------------------------------------- softmax
__global__ void softmax_k(const float* __restrict__ w1, const float* __restrict__ w2,
                          float* __restrict__ fbuf, float* __restrict__ out_tail) {
    int t = threadIdx.x;
    if (t < 2 * NC) {
        const float* w = (t < NC) ? w1 : w2;
        int c = t % NC;
        float v[JT];
        float mx = -1e30f;
        for (int j = 0; j < JT; ++j) { v[j] = w[c * JT + j]; mx = fmaxf(mx, v[j]); }
        float s = 0.f;
        for (int j = 0; j < JT; ++j) { v[j] = expf(v[j] - mx); s += v[j]; }
        float inv = 1.0f / s;
        for (int j = 0; j < JT; ++j) {
            float f = v[j] * inv;
            fbuf[t * JT + j] = f;       // rows: f1c0, f1c1, f2c0, f2c1
            out_tail[t * JT + j] = f;   // flat (f1, f2) output order
        }
    }
}

// ---------------------------------------------------------------- bf16 scatter
// Packed bf16 atomic add (gfx950 global_atomic_pk_add_bf16). The cell's pair
// partner receives +0.0bf16 (exact). Single-hit cells are bit-identical to
// fp32-accumulate-then-round; duplicate cells (~2%) accumulate in bf16.
__device__ __forceinline__ void pkadd(__bf16* base, size_t cell, float x) {
    uint16_t h = __builtin_bit_cast(uint16_t, (__bf16)x);
    uint32_t pk = (cell & 1) ? ((uint32_t)h << 16) : (uint32_t)h;
    __bf16* p = base + (cell & ~(size_t)1);
    asm volatile("global_atomic_pk_add_bf16 %0, %1, off"
                 :: "v"((uint64_t)(uintptr_t)p), "v"(pk) : "memory");
}

// One fused edge pass builds all four operand matrices-channels directly in
// bf16: A1 (rows = src), A2^T (rows = dst), each with 2 channels.
__global__ void scatter_pk_k(const int* __restrict__ ei, const float* __restrict__ ev,
                             const float* __restrict__ fbuf,
                             __bf16* __restrict__ A1, __bf16* __restrict__ A2) {
    int idx = blockIdx.x * blockDim.x + threadIdx.x;
    if (idx >= NNZ) return;
    int j = idx / NE;
    int e = idx - j * NE;
    int r = ei[(size_t)j * 2 * NE + e];
    int c = ei[(size_t)j * 2 * NE + NE + e];
    float v = ev[idx];
    float f10 = fbuf[j]          * v;   // f1 ch0
    float f11 = fbuf[JT + j]     * v;   // f1 ch1
    float f20 = fbuf[2 * JT + j] * v;   // f2 ch0
    float f21 = fbuf[3 * JT + j] * v;   // f2 ch1
    size_t rc = (size_t)r * NDIM + c;   // A1 cell
    size_t cr = (size_t)c * NDIM + r;   // A2^T cell
    pkadd(A1,       rc, f10);
    pkadd(A1 + MAT, rc, f11);
    pkadd(A2,       cr, f20);
    pkadd(A2 + MAT, cr, f21);
}

// ---------------------------------------------------------------- GEMM
// Round-2 verified kernel, verbatim: 256x256 8-phase, BK=64, 8 waves,
// 128 KiB dbuf LDS, counted vmcnt(2), XOR swizzle both-sides, setprio.
#define BM 256
#define BN 256
#define BK 64
#define NT (KDIM / BK)
#define TILE_E (BM * BK)

__device__ __forceinline__ void gl_lds16(const __bf16* g, __bf16* l) {
    __builtin_amdgcn_global_load_lds(
        (const __attribute__((address_space(1))) void*)(uintptr_t)g,
        (__attribute__((address_space(3))) void*)l, 16, 0, 0);
}

#define PHASE(MH, KS, READB, ...) do {                                            \
    _Pragma("unroll")                                                             \
    for (int i = 0; i < 4; ++i)                                                   \
        af[i] = *(const bf16x8*)(ldsAc +                                          \
            ((((rA + ((MH)*4 + i) * 16) * 128) + (KS)*64 + kb) ^ swz));           \
    if (READB) {                                                                  \
        _Pragma("unroll")                                                         \
        for (int n = 0; n < 4; ++n)                                               \
            bfr[n] = *(const bf16x8*)(ldsBc +                                     \
                ((((rB + n * 16) * 128) + (KS)*64 + kb) ^ swz));                  \
    }                                                                             \
    __VA_ARGS__;                                                                  \
    __builtin_amdgcn_s_barrier();                                                 \
    asm volatile("s_waitcnt lgkmcnt(0)" ::: "memory");                            \
    __builtin_amdgcn_s_setprio(1);                                                \
    _Pragma("unroll")                                                             \
    for (int i = 0; i < 4; ++i)                                                   \
        _Pragma("unroll")                                                         \
        for (int n = 0; n < 4; ++n)                                               \
            acc[(MH)*4 + i][n] = __builtin_amdgcn_mfma_f32_16x16x32_bf16(         \
                af[i], bfr[n], acc[(MH)*4 + i][n], 0, 0, 0);                      \
    __builtin_amdgcn_s_setprio(0);                                                \
    __builtin_amdgcn_s_barrier();                                                 \
} while (0)

__global__ __launch_bounds__(512, 2) void gemm_k(const __bf16* __restrict__ A,
                                                 const __bf16* __restrict__ B,
                                                 float* __restrict__ C) {
    __shared__ __align__(16) __bf16 sm[4 * TILE_E];

    const int u    = threadIdx.x;
    const int lane = u & 63;
    const int wv   = u >> 6;
    const int wm   = wv >> 2;
    const int wn   = wv & 3;
    const size_t matoff = (size_t)blockIdx.z * MAT;
    const size_t brow   = (size_t)blockIdx.y * BM;
    const size_t bcol   = (size_t)blockIdx.x * BN;

    const int srow = u >> 3;
    const int kc   = (u & 7) ^ (srow & 7);
    const __bf16* Abase = A + matoff + (brow + srow) * KDIM + kc * 8;
    const __bf16* Bbase = B + matoff + (bcol + srow) * KDIM + kc * 8;

    char* const smb = (char*)sm;
    auto issueA = [&](int unit, int tt) {
        const __bf16* src = Abase + (size_t)unit * 64 * KDIM + (size_t)tt * BK;
        __bf16* dst = (__bf16*)(smb + (tt & 1) * 65536 + unit * 8192 + wv * 1024);
        gl_lds16(src, dst);
    };
    auto issueB = [&](int unit, int tt) {
        const __bf16* src = Bbase + (size_t)unit * 64 * KDIM + (size_t)tt * BK;
        __bf16* dst = (__bf16*)(smb + (tt & 1) * 65536 + 32768 + unit * 8192 + wv * 1024);
        gl_lds16(src, dst);
    };

    const int rA  = wm * 128 + (lane & 15);
    const int rB  = wn * 64  + (lane & 15);
    const int kb  = (lane >> 4) * 16;
    const int swz = (lane & 7) << 4;

    f32x4 acc[8][4];
#pragma unroll
    for (int m = 0; m < 8; ++m)
#pragma unroll
        for (int n = 0; n < 4; ++n) acc[m][n] = (f32x4){0.f, 0.f, 0.f, 0.f};

    bf16x8 af[4], bfr[4];

#pragma unroll
    for (int i = 0; i < 4; ++i) issueA(i, 0);
#pragma unroll
    for (int i = 0; i < 4; ++i) issueB(i, 0);

    for (int t = 0; t < NT; ++t) {
        const char* ldsAc = smb + (t & 1) * 65536;
        const char* ldsBc = ldsAc + 32768;
        const int nxt = t + 1;
        const bool hasNext = nxt < NT;

        if (hasNext) {
            issueA(0, nxt); issueA(1, nxt);
            asm volatile("s_waitcnt vmcnt(2)" ::: "memory");
        } else {
            asm volatile("s_waitcnt vmcnt(0)" ::: "memory");
        }
        __builtin_amdgcn_s_barrier();
        asm volatile("" ::: "memory");

        PHASE(0, 0, true,  if (hasNext) { issueA(2, nxt); issueA(3, nxt);
                                          issueB(0, nxt); issueB(1, nxt); });
        PHASE(1, 0, false, if (hasNext) { issueB(2, nxt); issueB(3, nxt); });
        PHASE(0, 1, true,  );
        PHASE(1, 1, false, );
    }

    float* Cc = C + matoff;
#pragma unroll
    for (int m = 0; m < 8; ++m) {
        int orow0 = (int)brow + wm * 128 + m * 16 + (lane >> 4) * 4;
#pragma unroll
        for (int n = 0; n < 4; ++n) {
            int ocol = (int)bcol + wn * 64 + n * 16 + (lane & 15);
            float* p = Cc + (size_t)orow0 * NDIM + ocol;
#pragma unroll
            for (int jj = 0; jj < 4; ++jj) p[(size_t)jj * NDIM] = acc[m][n][jj];
        }
    }
}

// ---------------------------------------------------------------- launch
extern "C" void kernel_launch(void* const* d_in, const int* in_sizes, int n_in,
                              void* d_out, int out_size, void* d_ws, size_t ws_size,
                              hipStream_t stream) {
    const int*   ei = (const int*)d_in[0];
    const float* ev = (const float*)d_in[1];
    const float* w1 = (const float*)d_in[2];
    const float* w2 = (const float*)d_in[3];
    float* out = (float*)d_out;

    // ws: A1 bf16 (67MB, 2ch) | A2T bf16 (67MB, 2ch) | fbuf (20 floats)
    char* ws = (char*)d_ws;
    __bf16* A1b  = (__bf16*)ws;
    __bf16* A2b  = (__bf16*)(ws + HN * sizeof(__bf16));
    float*  fbuf = (float*)(ws + 2 * HN * sizeof(__bf16));
    size_t needed = 2 * HN * sizeof(__bf16) + 32 * sizeof(float);
    if (ws_size < needed) return;

    // 1. softmax weights
    softmax_k<<<dim3(1), dim3(64), 0, stream>>>(w1, w2, fbuf, out + HN);

    // 2. zero both bf16 operand buffers (contiguous, 134 MB)
    hipMemsetAsync(A1b, 0, 2 * HN * sizeof(__bf16), stream);

    // 3. one fused edge pass: 4 pk-bf16 atomics per edge
    const int nb = (NNZ + 255) / 256;
    scatter_pk_k<<<dim3(nb), dim3(256), 0, stream>>>(ei, ev, fbuf, A1b, A2b);

    // 4. H[c] = A1[c] @ A2[c]  (B operand pre-transposed)
    gemm_k<<<dim3(NDIM / BN, NDIM / BM, NC), dim3(512), 0, stream>>>(A1b, A2b, out);
}

// Round 7
// 357.957 us; speedup vs baseline: 4.3497x; 1.0827x over previous
//
#include <hip/hip_runtime.h>
#include <hip/hip_bf16.h>
#include <stdint.h>

// Problem constants (from reference setup_inputs)
#define JT 5           // edge types
#define NE 150000      // edges per type
#define NC 2           // channels
#define NDIM 4096      // nodes
#define KDIM 4096
#define NNZ (JT * NE)  // 750000 raw edges (duplicates fine: linearity == coalesce)
constexpr size_t MAT = (size_t)NDIM * NDIM;   // 16,777,216
constexpr size_t HN  = (size_t)NC * MAT;      // 33,554,432 (H element count)

typedef __bf16 bf16x8 __attribute__((ext_vector_type(8)));
typedef float  f32x4  __attribute__((ext_vector_type(4)));

// ---------------------------------------------------------------- softmax
__global__ void softmax_k(const float* __restrict__ w1, const float* __restrict__ w2,
                          float* __restrict__ fbuf, float* __restrict__ out_tail) {
    int t = threadIdx.x;
    if (t < 2 * NC) {
        const float* w = (t < NC) ? w1 : w2;
        int c = t % NC;
        float v[JT];
        float mx = -1e30f;
        for (int j = 0; j < JT; ++j) { v[j] = w[c * JT + j]; mx = fmaxf(mx, v[j]); }
        float s = 0.f;
        for (int j = 0; j < JT; ++j) { v[j] = expf(v[j] - mx); s += v[j]; }
        float inv = 1.0f / s;
        for (int j = 0; j < JT; ++j) {
            float f = v[j] * inv;
            fbuf[t * JT + j] = f;       // rows: f1c0, f1c1, f2c0, f2c1
            out_tail[t * JT + j] = f;   // flat (f1, f2) output order
        }
    }
}

// ---------------------------------------------------------------- scatter
// 4-channel interleaved cell matrix Xi[r][c] = {f1c0*v, f1c1*v, f2c0*v, f2c1*v}
// (4 x bf16 = 8 B). Both pk-atomics of an edge hit the SAME 64B line (1 line
// per edge vs 4 in the channel-separated layout).
__device__ __forceinline__ void pkadd2(__bf16* p, float lo, float hi) {
    uint16_t a = __builtin_bit_cast(uint16_t, (__bf16)lo);
    uint16_t b = __builtin_bit_cast(uint16_t, (__bf16)hi);
    uint32_t pk = ((uint32_t)b << 16) | a;   // lo -> [addr], hi -> [addr+2]
    asm volatile("global_atomic_pk_add_bf16 %0, %1, off"
                 :: "v"((uint64_t)(uintptr_t)p), "v"(pk) : "memory");
}

__global__ void scatter2_k(const int* __restrict__ ei, const float* __restrict__ ev,
                           const float* __restrict__ fbuf, __bf16* __restrict__ Xi) {
    int idx = blockIdx.x * blockDim.x + threadIdx.x;
    if (idx >= NNZ) return;
    int j = idx / NE;
    int e = idx - j * NE;
    int r = ei[(size_t)j * 2 * NE + e];
    int c = ei[(size_t)j * 2 * NE + NE + e];
    float v = ev[idx];
    size_t cell = ((size_t)r * NDIM + c) * 4;       // 4 bf16 per cell, 8B-aligned
    pkadd2(Xi + cell,     fbuf[j]          * v, fbuf[JT + j]     * v);  // f1 ch0,ch1
    pkadd2(Xi + cell + 2, fbuf[2 * JT + j] * v, fbuf[3 * JT + j] * v);  // f2 ch0,ch1
}

// ---------------------------------------------------------------- repack
// 64x64 cell tile per block: deinterleave Xi into A1[ch][r][c] (row-major)
// and A2T[ch][c][r] (transposed via LDS). Pure-BW pass: 134 MB R + 134 MB W.
__device__ __forceinline__ uint4 gather8(const ushort (*s)[65], int rr, int e8) {
    uint4 v;
    v.x = (uint32_t)s[rr][e8 + 0] | ((uint32_t)s[rr][e8 + 1] << 16);
    v.y = (uint32_t)s[rr][e8 + 2] | ((uint32_t)s[rr][e8 + 3] << 16);
    v.z = (uint32_t)s[rr][e8 + 4] | ((uint32_t)s[rr][e8 + 5] << 16);
    v.w = (uint32_t)s[rr][e8 + 6] | ((uint32_t)s[rr][e8 + 7] << 16);
    return v;
}

__global__ __launch_bounds__(256) void repack_k(const ushort4* __restrict__ Xi,
                                                __bf16* __restrict__ A1,
                                                __bf16* __restrict__ A2T) {
    __shared__ ushort s10[64][65];   // f1 ch0, [row][col]
    __shared__ ushort s11[64][65];   // f1 ch1, [row][col]
    __shared__ ushort s20[64][65];   // f2 ch0, [col][row]  (pre-transposed)
    __shared__ ushort s21[64][65];   // f2 ch1, [col][row]
    const int r0 = blockIdx.y * 64, c0 = blockIdx.x * 64;
    const int t = threadIdx.x;

#pragma unroll
    for (int it = 0; it < 16; ++it) {
        int li = t + 256 * it;              // 0..4095
        int rr = li >> 6, cc = li & 63;
        ushort4 v = Xi[(size_t)(r0 + rr) * NDIM + (c0 + cc)];
        s10[rr][cc] = v.x; s11[rr][cc] = v.y;
        s20[cc][rr] = v.z; s21[cc][rr] = v.w;
    }
    __syncthreads();

#pragma unroll
    for (int a = 0; a < 2; ++a) {
        int w = t + 256 * a;                // 0..511
        int rr = w >> 3, e8 = (w & 7) << 3; // row-in-tile, 8-elem chunk
        // A1: rows r0+rr, cols c0+e8.. (16B aligned: c0%64==0, e8%8==0)
        *(uint4*)(A1 +        (size_t)(r0 + rr) * NDIM + c0 + e8) = gather8(s10, rr, e8);
        *(uint4*)(A1 + MAT +  (size_t)(r0 + rr) * NDIM + c0 + e8) = gather8(s11, rr, e8);
        // A2T: rows c0+rr (from transposed LDS), cols r0+e8..
        *(uint4*)(A2T +       (size_t)(c0 + rr) * NDIM + r0 + e8) = gather8(s20, rr, e8);
        *(uint4*)(A2T + MAT + (size_t)(c0 + rr) * NDIM + r0 + e8) = gather8(s21, rr, e8);
    }
}

// ---------------------------------------------------------------- GEMM
// Round-2 verified kernel, verbatim: 256x256 8-phase, BK=64, 8 waves,
// 128 KiB dbuf LDS, counted vmcnt(2), XOR swizzle both-sides, setprio.
#define BM 256
#define BN 256
#define BK 64
#define NT (KDIM / BK)
#define TILE_E (BM * BK)

__device__ __forceinline__ void gl_lds16(const __bf16* g, __bf16* l) {
    __builtin_amdgcn_global_load_lds(
        (const __attribute__((address_space(1))) void*)(uintptr_t)g,
        (__attribute__((address_space(3))) void*)l, 16, 0, 0);
}

#define PHASE(MH, KS, READB, ...) do {                                            \
    _Pragma("unroll")                                                             \
    for (int i = 0; i < 4; ++i)                                                   \
        af[i] = *(const bf16x8*)(ldsAc +                                          \
            ((((rA + ((MH)*4 + i) * 16) * 128) + (KS)*64 + kb) ^ swz));           \
    if (READB) {                                                                  \
        _Pragma("unroll")                                                         \
        for (int n = 0; n < 4; ++n)                                               \
            bfr[n] = *(const bf16x8*)(ldsBc +                                     \
                ((((rB + n * 16) * 128) + (KS)*64 + kb) ^ swz));                  \
    }                                                                             \
    __VA_ARGS__;                                                                  \
    __builtin_amdgcn_s_barrier();                                                 \
    asm volatile("s_waitcnt lgkmcnt(0)" ::: "memory");                            \
    __builtin_amdgcn_s_setprio(1);                                                \
    _Pragma("unroll")                                                             \
    for (int i = 0; i < 4; ++i)                                                   \
        _Pragma("unroll")                                                         \
        for (int n = 0; n < 4; ++n)                                               \
            acc[(MH)*4 + i][n] = __builtin_amdgcn_mfma_f32_16x16x32_bf16(         \
                af[i], bfr[n], acc[(MH)*4 + i][n], 0, 0, 0);                      \
    __builtin_amdgcn_s_setprio(0);                                                \
    __builtin_amdgcn_s_barrier();                                                 \
} while (0)

__global__ __launch_bounds__(512, 2) void gemm_k(const __bf16* __restrict__ A,
                                                 const __bf16* __restrict__ B,
                                                 float* __restrict__ C) {
    __shared__ __align__(16) __bf16 sm[4 * TILE_E];

    const int u    = threadIdx.x;
    const int lane = u & 63;
    const int wv   = u >> 6;
    const int wm   = wv >> 2;
    const int wn   = wv & 3;
    const size_t matoff = (size_t)blockIdx.z * MAT;
    const size_t brow   = (size_t)blockIdx.y * BM;
    const size_t bcol   = (size_t)blockIdx.x * BN;

    const int srow = u >> 3;
    const int kc   = (u & 7) ^ (srow & 7);
    const __bf16* Abase = A + matoff + (brow + srow) * KDIM + kc * 8;
    const __bf16* Bbase = B + matoff + (bcol + srow) * KDIM + kc * 8;

    char* const smb = (char*)sm;
    auto issueA = [&](int unit, int tt) {
        const __bf16* src = Abase + (size_t)unit * 64 * KDIM + (size_t)tt * BK;
        __bf16* dst = (__bf16*)(smb + (tt & 1) * 65536 + unit * 8192 + wv * 1024);
        gl_lds16(src, dst);
    };
    auto issueB = [&](int unit, int tt) {
        const __bf16* src = Bbase + (size_t)unit * 64 * KDIM + (size_t)tt * BK;
        __bf16* dst = (__bf16*)(smb + (tt & 1) * 65536 + 32768 + unit * 8192 + wv * 1024);
        gl_lds16(src, dst);
    };

    const int rA  = wm * 128 + (lane & 15);
    const int rB  = wn * 64  + (lane & 15);
    const int kb  = (lane >> 4) * 16;
    const int swz = (lane & 7) << 4;

    f32x4 acc[8][4];
#pragma unroll
    for (int m = 0; m < 8; ++m)
#pragma unroll
        for (int n = 0; n < 4; ++n) acc[m][n] = (f32x4){0.f, 0.f, 0.f, 0.f};

    bf16x8 af[4], bfr[4];

#pragma unroll
    for (int i = 0; i < 4; ++i) issueA(i, 0);
#pragma unroll
    for (int i = 0; i < 4; ++i) issueB(i, 0);

    for (int t = 0; t < NT; ++t) {
        const char* ldsAc = smb + (t & 1) * 65536;
        const char* ldsBc = ldsAc + 32768;
        const int nxt = t + 1;
        const bool hasNext = nxt < NT;

        if (hasNext) {
            issueA(0, nxt); issueA(1, nxt);
            asm volatile("s_waitcnt vmcnt(2)" ::: "memory");
        } else {
            asm volatile("s_waitcnt vmcnt(0)" ::: "memory");
        }
        __builtin_amdgcn_s_barrier();
        asm volatile("" ::: "memory");

        PHASE(0, 0, true,  if (hasNext) { issueA(2, nxt); issueA(3, nxt);
                                          issueB(0, nxt); issueB(1, nxt); });
        PHASE(1, 0, false, if (hasNext) { issueB(2, nxt); issueB(3, nxt); });
        PHASE(0, 1, true,  );
        PHASE(1, 1, false, );
    }

    float* Cc = C + matoff;
#pragma unroll
    for (int m = 0; m < 8; ++m) {
        int orow0 = (int)brow + wm * 128 + m * 16 + (lane >> 4) * 4;
#pragma unroll
        for (int n = 0; n < 4; ++n) {
            int ocol = (int)bcol + wn * 64 + n * 16 + (lane & 15);
            float* p = Cc + (size_t)orow0 * NDIM + ocol;
#pragma unroll
            for (int jj = 0; jj < 4; ++jj) p[(size_t)jj * NDIM] = acc[m][n][jj];
        }
    }
}

// ---------------------------------------------------------------- launch
extern "C" void kernel_launch(void* const* d_in, const int* in_sizes, int n_in,
                              void* d_out, int out_size, void* d_ws, size_t ws_size,
                              hipStream_t stream) {
    const int*   ei = (const int*)d_in[0];
    const float* ev = (const float*)d_in[1];
    const float* w1 = (const float*)d_in[2];
    const float* w2 = (const float*)d_in[3];
    float* out = (float*)d_out;

    // ws: A1 bf16 (67MB, 2ch) | A2T bf16 (67MB, 2ch) | fbuf (20 floats)
    char* ws = (char*)d_ws;
    __bf16* A1b  = (__bf16*)ws;
    __bf16* A2b  = (__bf16*)(ws + HN * sizeof(__bf16));
    float*  fbuf = (float*)(ws + 2 * HN * sizeof(__bf16));
    size_t needed = 2 * HN * sizeof(__bf16) + 32 * sizeof(float);
    if (ws_size < needed) return;

    // Xi (4-ch interleaved cell matrix, 134 MB) lives in the dead H region of
    // d_out; the GEMM overwrites it last.
    __bf16* Xi = (__bf16*)d_out;

    // 1. softmax weights (also writes f1,f2 output tail)
    softmax_k<<<dim3(1), dim3(64), 0, stream>>>(w1, w2, fbuf, out + HN);

    // 2. zero the cell matrix (MAT cells x 8 B = HN x 4 B)
    hipMemsetAsync(Xi, 0, HN * sizeof(float), stream);

    // 3. one edge pass: 2 adjacent pk-bf16 atomics per edge (1 line/edge)
    const int nb = (NNZ + 255) / 256;
    scatter2_k<<<dim3(nb), dim3(256), 0, stream>>>(ei, ev, fbuf, Xi);

    // 4. deinterleave/transpose into GEMM operands (pure-BW tiled pass)
    repack_k<<<dim3(64, 64), dim3(256), 0, stream>>>((const ushort4*)Xi, A1b, A2b);

    // 5. H[c] = A1[c] @ A2[c]  (B operand pre-transposed)
    gemm_k<<<dim3(NDIM / BN, NDIM / BM, NC), dim3(512), 0, stream>>>(A1b, A2b, out);
}

// Round 8
// 338.503 us; speedup vs baseline: 4.5997x; 1.0575x over previous
//
#include <hip/hip_runtime.h>
#include <hip/hip_bf16.h>
#include <stdint.h>

// Problem constants (from reference setup_inputs)
#define JT 5           // edge types
#define NE 150000      // edges per type
#define NC 2           // channels
#define NDIM 4096      // nodes
#define KDIM 4096
#define NNZ (JT * NE)  // 750000 raw edges (duplicates fine: linearity == coalesce)
constexpr size_t MAT = (size_t)NDIM * NDIM;   // 16,777,216
constexpr size_t HN  = (size_t)NC * MAT;      // 33,554,432 (H element count)

typedef __bf16 bf16x8 __attribute__((ext_vector_type(8)));
typedef float  f32x4  __attribute__((ext_vector_type(4)));

// ---------------------------------------------------------------- softmax
__global__ void softmax_k(const float* __restrict__ w1, const float* __restrict__ w2,
                          float* __restrict__ fbuf, float* __restrict__ out_tail) {
    int t = threadIdx.x;
    if (t < 2 * NC) {
        const float* w = (t < NC) ? w1 : w2;
        int c = t % NC;
        float v[JT];
        float mx = -1e30f;
        for (int j = 0; j < JT; ++j) { v[j] = w[c * JT + j]; mx = fmaxf(mx, v[j]); }
        float s = 0.f;
        for (int j = 0; j < JT; ++j) { v[j] = expf(v[j] - mx); s += v[j]; }
        float inv = 1.0f / s;
        for (int j = 0; j < JT; ++j) {
            float f = v[j] * inv;
            fbuf[t * JT + j] = f;       // rows: f1c0, f1c1, f2c0, f2c1
            out_tail[t * JT + j] = f;   // flat (f1, f2) output order
        }
    }
}

// ---------------------------------------------------------------- scatter
// 4-channel interleaved cell matrix Xi[r][c] = {f1c0*v, f1c1*v, f2c0*v, f2c1*v}
// (4 x bf16 = 8 B). Both pk-atomics of an edge hit the SAME 64B line.
__device__ __forceinline__ void pkadd2(__bf16* p, float lo, float hi) {
    uint16_t a = __builtin_bit_cast(uint16_t, (__bf16)lo);
    uint16_t b = __builtin_bit_cast(uint16_t, (__bf16)hi);
    uint32_t pk = ((uint32_t)b << 16) | a;   // lo -> [addr], hi -> [addr+2]
    asm volatile("global_atomic_pk_add_bf16 %0, %1, off"
                 :: "v"((uint64_t)(uintptr_t)p), "v"(pk) : "memory");
}

__global__ void scatter2_k(const int* __restrict__ ei, const float* __restrict__ ev,
                           const float* __restrict__ fbuf, __bf16* __restrict__ Xi) {
    int idx = blockIdx.x * blockDim.x + threadIdx.x;
    if (idx >= NNZ) return;
    int j = idx / NE;
    int e = idx - j * NE;
    int r = ei[(size_t)j * 2 * NE + e];
    int c = ei[(size_t)j * 2 * NE + NE + e];
    float v = ev[idx];
    size_t cell = ((size_t)r * NDIM + c) * 4;       // 4 bf16 per cell, 8B-aligned
    pkadd2(Xi + cell,     fbuf[j]          * v, fbuf[JT + j]     * v);  // f1 ch0,ch1
    pkadd2(Xi + cell + 2, fbuf[2 * JT + j] * v, fbuf[3 * JT + j] * v);  // f2 ch0,ch1
}

// ---------------------------------------------------------------- repack
// 64x64 cell tile per block: deinterleave Xi into A1[ch][r][c] (row-major)
// and A2T[ch][c][r] (transposed via LDS). Pure-BW pass.
__device__ __forceinline__ uint4 gather8(const ushort (*s)[65], int rr, int e8) {
    uint4 v;
    v.x = (uint32_t)s[rr][e8 + 0] | ((uint32_t)s[rr][e8 + 1] << 16);
    v.y = (uint32_t)s[rr][e8 + 2] | ((uint32_t)s[rr][e8 + 3] << 16);
    v.z = (uint32_t)s[rr][e8 + 4] | ((uint32_t)s[rr][e8 + 5] << 16);
    v.w = (uint32_t)s[rr][e8 + 6] | ((uint32_t)s[rr][e8 + 7] << 16);
    return v;
}

__global__ __launch_bounds__(256) void repack_k(const ushort4* __restrict__ Xi,
                                                __bf16* __restrict__ A1,
                                                __bf16* __restrict__ A2T) {
    __shared__ ushort s10[64][65];   // f1 ch0, [row][col]
    __shared__ ushort s11[64][65];   // f1 ch1, [row][col]
    __shared__ ushort s20[64][65];   // f2 ch0, [col][row]  (pre-transposed)
    __shared__ ushort s21[64][65];   // f2 ch1, [col][row]
    const int r0 = blockIdx.y * 64, c0 = blockIdx.x * 64;
    const int t = threadIdx.x;

#pragma unroll
    for (int it = 0; it < 16; ++it) {
        int li = t + 256 * it;              // 0..4095
        int rr = li >> 6, cc = li & 63;
        ushort4 v = Xi[(size_t)(r0 + rr) * NDIM + (c0 + cc)];
        s10[rr][cc] = v.x; s11[rr][cc] = v.y;
        s20[cc][rr] = v.z; s21[cc][rr] = v.w;
    }
    __syncthreads();

#pragma unroll
    for (int a = 0; a < 2; ++a) {
        int w = t + 256 * a;                // 0..511
        int rr = w >> 3, e8 = (w & 7) << 3; // row-in-tile, 8-elem chunk
        *(uint4*)(A1 +        (size_t)(r0 + rr) * NDIM + c0 + e8) = gather8(s10, rr, e8);
        *(uint4*)(A1 + MAT +  (size_t)(r0 + rr) * NDIM + c0 + e8) = gather8(s11, rr, e8);
        *(uint4*)(A2T +       (size_t)(c0 + rr) * NDIM + r0 + e8) = gather8(s20, rr, e8);
        *(uint4*)(A2T + MAT + (size_t)(c0 + rr) * NDIM + r0 + e8) = gather8(s21, rr, e8);
    }
}

// ---------------------------------------------------------------- GEMM
// 256x256, BK=64, 8 waves. NEW: quadrant phases + half-tile staging with
// per-phase counted vmcnt gates (deep pipeline, m201-style, derived waits).
// Phase q=(AH,BH) computes C quadrant [AH*128,+128)x[BH*128,+128); each wave
// owns a 64x32 sub-block => 16 MFMA/phase, acc[2][2][4][2].
// Stage order per tile t (for t+1): P0->A0, P1->B0, P2->B1, P3->A1.
// Gates: vmcnt(4) at P0/P1/P2 (each waits a half staged >=3 phases earlier,
// 4-6 loads stay in flight); P3 gate-free & barrier-free.
// Hazard ledger: stage X(t+1) overwrites X(t-1); its readers drained per-wave
// at lgkmcnt(0) before their MFMA and globally before >=1 intervening
// s_barrier; stages sit after the phase barrier. Last tile peeled with
// vmcnt(4)/(2)/(0).
#define BM 256
#define BN 256
#define BK 64
#define NT (KDIM / BK)

__device__ __forceinline__ void gl_lds16(const __bf16* g, __bf16* l) {
    __builtin_amdgcn_global_load_lds(
        (const __attribute__((address_space(1))) void*)(uintptr_t)g,
        (__attribute__((address_space(3))) void*)l, 16, 0, 0);
}

#define READA(AH) do {                                                            \
    _Pragma("unroll")                                                             \
    for (int i = 0; i < 4; ++i)                                                   \
        _Pragma("unroll")                                                         \
        for (int ks = 0; ks < 2; ++ks)                                            \
            af[i][ks] = *(const bf16x8*)(ldsAc + (AH) * 16384 +                   \
                ((((rAl + i * 16) * 128) + ks * 64 + kb) ^ swz));                 \
} while (0)

#define READB(BH) do {                                                            \
    _Pragma("unroll")                                                             \
    for (int n = 0; n < 2; ++n)                                                   \
        _Pragma("unroll")                                                         \
        for (int ks = 0; ks < 2; ++ks)                                            \
            bf_[n][ks] = *(const bf16x8*)(ldsBc + (BH) * 16384 +                  \
                ((((rBl + n * 16) * 128) + ks * 64 + kb) ^ swz));                 \
} while (0)

#define MFMA16(AH, BH) do {                                                       \
    asm volatile("s_waitcnt lgkmcnt(0)" ::: "memory");                            \
    __builtin_amdgcn_s_setprio(1);                                                \
    _Pragma("unroll")                                                             \
    for (int i = 0; i < 4; ++i)                                                   \
        _Pragma("unroll")                                                         \
        for (int n = 0; n < 2; ++n)                                               \
            _Pragma("unroll")                                                     \
            for (int ks = 0; ks < 2; ++ks)                                        \
                acc[AH][BH][i][n] = __builtin_amdgcn_mfma_f32_16x16x32_bf16(      \
                    af[i][ks], bf_[n][ks], acc[AH][BH][i][n], 0, 0, 0);           \
    __builtin_amdgcn_s_setprio(0);                                                \
} while (0)

#define GATE_BAR(N) do {                                                          \
    asm volatile("s_waitcnt vmcnt(" #N ")" ::: "memory");                         \
    __builtin_amdgcn_s_barrier();                                                 \
    asm volatile("" ::: "memory");                                                \
} while (0)

__global__ __launch_bounds__(512, 2) void gemm_k(const __bf16* __restrict__ A,
                                                 const __bf16* __restrict__ B,
                                                 float* __restrict__ C) {
    // [buf][A half0|half1 | B half0|half1], buf = 64 KiB, total 128 KiB
    __shared__ __align__(16) __bf16 sm[65536];

    const int u    = threadIdx.x;       // 0..511
    const int lane = u & 63;
    const int wv   = u >> 6;            // wave 0..7
    const int wr   = (wv >> 2) * 64;    // wave row offset within 128-row quadrant
    const int wc   = (wv & 3) * 32;     // wave col offset within 128-col quadrant
    const size_t matoff = (size_t)blockIdx.z * MAT;
    const size_t brow   = (size_t)blockIdx.y * BM;
    const size_t bcol   = (size_t)blockIdx.x * BN;

    // staging: unit = 64 rows x 64 k = one 512-thread x 16B gl_lds (8 KiB);
    // half = 2 units (128 rows). Global source pre-inverse-swizzled.
    const int srow = u >> 3;                       // row within unit, 0..63
    const int kc   = (u & 7) ^ (srow & 7);         // inverse-swizzled k-chunk
    const __bf16* Ab = A + matoff + (brow + srow) * KDIM + kc * 8;
    const __bf16* Bb = B + matoff + (bcol + srow) * KDIM + kc * 8;
    char* const smb = (char*)sm;

    auto stage = [&](int mat, int h, int tt) {
        const __bf16* base = mat ? Bb : Ab;
#pragma unroll
        for (int unit = 0; unit < 2; ++unit) {
            const __bf16* src = base + (size_t)(h * 128 + unit * 64) * KDIM + (size_t)tt * BK;
            __bf16* dst = (__bf16*)(smb + (tt & 1) * 65536 + mat * 32768 +
                                    h * 16384 + unit * 8192 + wv * 1024);
            gl_lds16(src, dst);
        }
    };

    const int rAl = wr + (lane & 15);   // A row-in-half (+ i*16)
    const int rBl = wc + (lane & 15);   // B row-in-half (+ n*16)
    const int kb  = (lane >> 4) * 16;   // byte offset of lane's k-octet
    const int swz = (lane & 7) << 4;    // XOR swizzle mask

    f32x4 acc[2][2][4][2];
#pragma unroll
    for (int a = 0; a < 2; ++a)
#pragma unroll
        for (int b = 0; b < 2; ++b)
#pragma unroll
            for (int i = 0; i < 4; ++i)
#pragma unroll
                for (int n = 0; n < 2; ++n) acc[a][b][i][n] = (f32x4){0.f, 0.f, 0.f, 0.f};

    bf16x8 af[4][2], bf_[2][2];

    // prologue: tile 0's halves in first-use order A0, B0, B1, A1
    stage(0, 0, 0); stage(1, 0, 0); stage(1, 1, 0); stage(0, 1, 0);

    for (int t = 0; t < NT - 1; ++t) {
        const char* ldsAc = smb + (t & 1) * 65536;
        const char* ldsBc = ldsAc + 32768;
        const int nxt = t + 1;
        // P0: quadrant (A0,B0)
        GATE_BAR(4);
        stage(0, 0, nxt);
        READA(0); READB(0);
        MFMA16(0, 0);
        // P1: quadrant (A0,B1) — reuse af
        GATE_BAR(4);
        stage(1, 0, nxt);
        READB(1);
        MFMA16(0, 1);
        // P2: quadrant (A1,B1) — reuse bf_
        GATE_BAR(4);
        stage(1, 1, nxt);
        READA(1);
        MFMA16(1, 1);
        // P3: quadrant (A1,B0) — no gate, no barrier (operands gated at P0)
        stage(0, 1, nxt);
        READB(0);
        MFMA16(1, 0);
    }
    {   // peeled last tile: no stages, tightening gates
        const char* ldsAc = smb + ((NT - 1) & 1) * 65536;
        const char* ldsBc = ldsAc + 32768;
        GATE_BAR(4);
        READA(0); READB(0);
        MFMA16(0, 0);
        GATE_BAR(2);
        READB(1);
        MFMA16(0, 1);
        GATE_BAR(0);
        READA(1);
        MFMA16(1, 1);
        READB(0);
        MFMA16(1, 0);
    }

    // epilogue: C/D layout col = lane&15, row = (lane>>4)*4 + reg
    float* Cc = C + matoff;
#pragma unroll
    for (int a = 0; a < 2; ++a)
#pragma unroll
        for (int b = 0; b < 2; ++b)
#pragma unroll
            for (int i = 0; i < 4; ++i) {
                int orow0 = (int)brow + a * 128 + wr + i * 16 + (lane >> 4) * 4;
#pragma unroll
                for (int n = 0; n < 2; ++n) {
                    int ocol = (int)bcol + b * 128 + wc + n * 16 + (lane & 15);
                    float* p = Cc + (size_t)orow0 * NDIM + ocol;
#pragma unroll
                    for (int jj = 0; jj < 4; ++jj) p[(size_t)jj * NDIM] = acc[a][b][i][n][jj];
                }
            }
}

// ---------------------------------------------------------------- launch
extern "C" void kernel_launch(void* const* d_in, const int* in_sizes, int n_in,
                              void* d_out, int out_size, void* d_ws, size_t ws_size,
                              hipStream_t stream) {
    const int*   ei = (const int*)d_in[0];
    const float* ev = (const float*)d_in[1];
    const float* w1 = (const float*)d_in[2];
    const float* w2 = (const float*)d_in[3];
    float* out = (float*)d_out;

    // ws: A1 bf16 (67MB, 2ch) | A2T bf16 (67MB, 2ch) | fbuf (20 floats)
    char* ws = (char*)d_ws;
    __bf16* A1b  = (__bf16*)ws;
    __bf16* A2b  = (__bf16*)(ws + HN * sizeof(__bf16));
    float*  fbuf = (float*)(ws + 2 * HN * sizeof(__bf16));
    size_t needed = 2 * HN * sizeof(__bf16) + 32 * sizeof(float);
    if (ws_size < needed) return;

    // Xi (4-ch interleaved cell matrix, 134 MB) lives in the dead H region of
    // d_out; the GEMM overwrites it last.
    __bf16* Xi = (__bf16*)d_out;

    softmax_k<<<dim3(1), dim3(64), 0, stream>>>(w1, w2, fbuf, out + HN);

    hipMemsetAsync(Xi, 0, HN * sizeof(float), stream);

    const int nb = (NNZ + 255) / 256;
    scatter2_k<<<dim3(nb), dim3(256), 0, stream>>>(ei, ev, fbuf, Xi);

    repack_k<<<dim3(64, 64), dim3(256), 0, stream>>>((const ushort4*)Xi, A1b, A2b);

    gemm_k<<<dim3(NDIM / BN, NDIM / BM, NC), dim3(512), 0, stream>>>(A1b, A2b, out);
}